// Round 1
// baseline (139.847 us; speedup 1.0000x reference)
//
#include <hip/hip_runtime.h>
#include <math.h>

#define NN 2048
#define BB 4
#define HD 128
#define CNUM 8
#define WPB 4               // waves (= centers) per block in k_dist
#define CAP 64              // reverse-adjacency slots per node (avg in-degree = 3)
#define NPB 8               // nodes per block in k_conv2 (2 parallel x 4 iters)
#define NCH (NN / NPB)      // partial-max chunks per batch

typedef unsigned long long u64;

// Branchless top-3: packed key (float-bits(sq) << 32) | j. sq >= 0 so IEEE
// bits are monotonic; u64 order == (sq, j) lexicographic == reference
// tie-break (lowest j wins).
__device__ __forceinline__ u64 pack_key(float sq, int j) {
    return ((u64)__float_as_uint(sq) << 32) | (unsigned)j;
}
__device__ __forceinline__ void ins3(u64 k, u64& k0, u64& k1, u64& k2) {
    u64 a = k  < k2 ? k  : k2;   // survivor of {k, k2}
    u64 b = k0 > a  ? k0 : a;    // merge a into sorted (k0, k1)
    k0    = k0 < a  ? k0 : a;
    k2    = k1 > b  ? k1 : b;
    k1    = k1 < b  ? k1 : b;
}

// K1: one wave per center. Points staged once per block into LDS (fuses old
// k_prep). Branchless top-3, butterfly merge, fused exp/de/dv epilogue, and
// reverse-adjacency build (3 counter atomics per wave -- replaces 6.2M f32
// atomics in the old scatter convs).
__global__ __launch_bounds__(256) void k_dist(
        const float* __restrict__ x,
        int* __restrict__ idx, float* __restrict__ vals,
        float* __restrict__ de, float* __restrict__ dv,
        int* __restrict__ cnt, int2* __restrict__ rev) {
    __shared__ float4 sp[NN];                       // 32 KB -> 5 blocks/CU
    const int b = blockIdx.y;
    const float* xb = x + (size_t)b * NN * 3;
    for (int q = threadIdx.x; q < NN; q += 256) {   // stage + pack |p|^2
        const float a = xb[3 * q], c = xb[3 * q + 1], d = xb[3 * q + 2];
        sp[q] = make_float4(a, c, d, a * a + c * c + d * d);
    }
    __syncthreads();

    const int wave = threadIdx.x >> 6;
    const int lane = threadIdx.x & 63;
    const int i = blockIdx.x * WPB + wave;          // this wave's center
    const float4 ci = sp[i];
    u64 k0 = ~0ull, k1 = ~0ull, k2 = ~0ull;
    float dsA = 0.f, dsB = 0.f;
    for (int t = lane; t < NN; t += 256) {          // 8 iterations, 4 elems each
        const float4 pa = sp[t];
        const float4 pv = sp[t + 64];
        const float4 pc = sp[t + 128];
        const float4 pd = sp[t + 192];
        const float qa = fmaxf(ci.w + pa.w - 2.0f * (ci.x * pa.x + ci.y * pa.y + ci.z * pa.z), 0.0f);
        const float qb = fmaxf(ci.w + pv.w - 2.0f * (ci.x * pv.x + ci.y * pv.y + ci.z * pv.z), 0.0f);
        const float qc = fmaxf(ci.w + pc.w - 2.0f * (ci.x * pc.x + ci.y * pc.y + ci.z * pc.z), 0.0f);
        const float qd = fmaxf(ci.w + pd.w - 2.0f * (ci.x * pd.x + ci.y * pd.y + ci.z * pd.z), 0.0f);
        dsA += __builtin_amdgcn_sqrtf(qa + 1e-12f) + __builtin_amdgcn_sqrtf(qc + 1e-12f);
        dsB += __builtin_amdgcn_sqrtf(qb + 1e-12f) + __builtin_amdgcn_sqrtf(qd + 1e-12f);
        ins3(pack_key(qa, t),       k0, k1, k2);
        ins3(pack_key(qb, t + 64),  k0, k1, k2);
        ins3(pack_key(qc, t + 128), k0, k1, k2);
        ins3(pack_key(qd, t + 192), k0, k1, k2);
    }
    float dsum = dsA + dsB;
    // butterfly merge: packed keys are globally unique -> plain u64 merge
    for (int off = 32; off > 0; off >>= 1) {
        const u64 o0 = __shfl_xor(k0, off);
        const u64 o1 = __shfl_xor(k1, off);
        const u64 o2 = __shfl_xor(k2, off);
        dsum += __shfl_xor(dsum, off);
        ins3(o0, k0, k1, k2);
        ins3(o1, k0, k1, k2);
        ins3(o2, k0, k1, k2);
    }
    if (lane == 0) {
        const float s0 = __uint_as_float((unsigned)(k0 >> 32));
        const float s1 = __uint_as_float((unsigned)(k1 >> 32));
        const float s2 = __uint_as_float((unsigned)(k2 >> 32));
        const int   i0 = (int)(k0 & 0xffffffffu);
        const int   i1 = (int)(k1 & 0xffffffffu);
        const int   i2 = (int)(k2 & 0xffffffffu);
        const float avg = dsum * (1.0f / NN);
        const float inva2 = 1.0f / (avg * avg);
        const float v0 = expf(-s0 * inva2);
        const float v1 = expf(-s1 * inva2);
        const float v2 = expf(-s2 * inva2);
        const int base = (b * NN + i) * 3;
        idx[base] = i0; idx[base + 1] = i1; idx[base + 2] = i2;
        vals[base] = v0; vals[base + 1] = v1; vals[base + 2] = v2;
        de[b * NN + i] = v0 + v1 + v2;
        atomicAdd(&dv[b * NN + i0], v0);
        atomicAdd(&dv[b * NN + i1], v1);
        atomicAdd(&dv[b * NN + i2], v2);
        // reverse adjacency: node j <- (edge i, coeff v). 3 tiny int atomics.
        const int p0 = atomicAdd(&cnt[b * NN + i0], 1);
        if (p0 < CAP) rev[((size_t)(b * NN + i0)) * CAP + p0] = make_int2(i, __float_as_int(v0));
        const int p1 = atomicAdd(&cnt[b * NN + i1], 1);
        if (p1 < CAP) rev[((size_t)(b * NN + i1)) * CAP + p1] = make_int2(i, __float_as_int(v1));
        const int p2 = atomicAdd(&cnt[b * NN + i2], 1);
        if (p2 < CAP) rev[((size_t)(b * NN + i2)) * CAP + p2] = make_int2(i, __float_as_int(v2));
    }
}

// K2: f1 = G @ W1 + b1, pure gather. Per node i, loop over incoming edges
// (avg 3), recompute the edge vector y_e on the fly (3 fma x 3 rows),
// accumulate v * y_e. No atomics, no Z buffers, plain coalesced store.
__global__ __launch_bounds__(256) void k_conv1(
        const float* __restrict__ W1, const float* __restrict__ b1,
        const int* __restrict__ idx, const float* __restrict__ vals,
        const float* __restrict__ de, const float* __restrict__ dv,
        const int* __restrict__ cnt, const int2* __restrict__ rev,
        float* __restrict__ f1) {
    const int b = blockIdx.y;
    const int i = blockIdx.x * 2 + (threadIdx.x >> 7);
    const int h = threadIdx.x & (HD - 1);
    const int ni = b * NN + i;
    const int cn = min(cnt[ni], CAP);
    float acc = 0.f;
    for (int s = 0; s < cn; ++s) {
        const int2 r = rev[(size_t)ni * CAP + s];
        const int e = r.x;
        const float v = __int_as_float(r.y);
        const int eb = (b * NN + e) * 3;
        const int j0 = idx[eb], j1 = idx[eb + 1], j2 = idx[eb + 2];
        const float v0 = vals[eb], v1 = vals[eb + 1], v2 = vals[eb + 2];
        const float ide = 1.0f / de[b * NN + e];
        const float g0 = v0 * rsqrtf(dv[b * NN + j0]);
        const float g1 = v1 * rsqrtf(dv[b * NN + j1]);
        const float g2 = v2 * rsqrtf(dv[b * NN + j2]);
        const float y = ide * (g0 * W1[j0 * HD + h] + g1 * W1[j1 * HD + h] + g2 * W1[j2 * HD + h]);
        acc += v * y;
    }
    f1[(size_t)ni * HD + h] = rsqrtf(dv[ni]) * acc + b1[h];
}

// K3: out = G @ f1, same gather, fused chunk-max (old k_pool1). Each block
// covers NPB nodes (2 in parallel across the half-blocks, NPB/2 serial),
// keeps a running max, merges halves in LDS, writes one pmax row.
__global__ __launch_bounds__(256) void k_conv2(
        const int* __restrict__ idx, const float* __restrict__ vals,
        const float* __restrict__ de, const float* __restrict__ dv,
        const int* __restrict__ cnt, const int2* __restrict__ rev,
        const float* __restrict__ f1, float* __restrict__ pmax) {
    __shared__ float smx[2][HD];
    const int b = blockIdx.y;
    const int sub = threadIdx.x >> 7;
    const int h = threadIdx.x & (HD - 1);
    float mx = -INFINITY;
    for (int t = 0; t < NPB / 2; ++t) {
        const int i = blockIdx.x * NPB + t * 2 + sub;
        const int ni = b * NN + i;
        const int cn = min(cnt[ni], CAP);
        float acc = 0.f;
        for (int s = 0; s < cn; ++s) {
            const int2 r = rev[(size_t)ni * CAP + s];
            const int e = r.x;
            const float v = __int_as_float(r.y);
            const int eb = (b * NN + e) * 3;
            const int j0 = idx[eb], j1 = idx[eb + 1], j2 = idx[eb + 2];
            const float v0 = vals[eb], v1 = vals[eb + 1], v2 = vals[eb + 2];
            const float ide = 1.0f / de[b * NN + e];
            const float g0 = v0 * rsqrtf(dv[b * NN + j0]);
            const float g1 = v1 * rsqrtf(dv[b * NN + j1]);
            const float g2 = v2 * rsqrtf(dv[b * NN + j2]);
            const float y = ide * (g0 * f1[((size_t)(b * NN + j0)) * HD + h]
                                 + g1 * f1[((size_t)(b * NN + j1)) * HD + h]
                                 + g2 * f1[((size_t)(b * NN + j2)) * HD + h]);
            acc += v * y;
        }
        mx = fmaxf(mx, rsqrtf(dv[ni]) * acc);
    }
    smx[sub][h] = mx;
    __syncthreads();
    if (sub == 0)
        pmax[((size_t)b * NCH + blockIdx.x) * HD + h] = fmaxf(smx[0][h], smx[1][h]);
}

// K4: merge partial maxes + classifier. grid B x 256 threads.
__global__ void k_pool2(const float* __restrict__ Wc, const float* __restrict__ bc,
                        const float* __restrict__ pmax, float* __restrict__ out) {
    __shared__ float s2[2][HD];
    const int b = blockIdx.x;
    const int h = threadIdx.x & (HD - 1);
    const int half = threadIdx.x >> 7;
    float mx = -INFINITY;
    for (int c = half; c < NCH; c += 2)
        mx = fmaxf(mx, pmax[((size_t)b * NCH + c) * HD + h]);
    s2[half][h] = mx;
    __syncthreads();
    if (half == 0) s2[0][h] = fmaxf(s2[0][h], s2[1][h]);
    __syncthreads();
    if (threadIdx.x < CNUM) {
        float acc = bc[threadIdx.x];
        for (int q = 0; q < HD; ++q) acc += s2[0][q] * Wc[q * CNUM + threadIdx.x];
        out[b * CNUM + threadIdx.x] = acc;
    }
}

extern "C" void kernel_launch(void* const* d_in, const int* in_sizes, int n_in,
                              void* d_out, int out_size, void* d_ws, size_t ws_size,
                              hipStream_t stream) {
    const float* x  = (const float*)d_in[0];   // [B,N,3]
    const float* W1 = (const float*)d_in[1];   // [N,H1]
    const float* b1 = (const float*)d_in[2];   // [H1]
    const float* Wc = (const float*)d_in[3];   // [H1,C]
    const float* bc = (const float*)d_in[4];   // [C]
    float* out = (float*)d_out;                // [B,C]

    float* ws = (float*)d_ws;
    float* dv   = ws;                                  // B*N           (zeroed)
    int*   cnt  = (int*)(dv + BB * NN);                // B*N           (zeroed)
    float* de   = (float*)(cnt + BB * NN);             // B*N
    int*   idx  = (int*)(de + BB * NN);                // B*N*3
    float* vals = (float*)(idx + BB * NN * 3);         // B*N*3
    int2*  rev  = (int2*)(vals + BB * NN * 3);         // B*N*CAP int2
    float* f1   = (float*)(rev + (size_t)BB * NN * CAP); // B*N*HD
    float* pmax = f1 + (size_t)BB * NN * HD;           // B*NCH*HD

    // zero only [dv | cnt] (64 KB) -- Z1/Z2 scatter targets are gone
    hipMemsetAsync(dv, 0, (size_t)2 * BB * NN * sizeof(float), stream);

    k_dist <<<dim3(NN / WPB, BB), 256, 0, stream>>>(x, idx, vals, de, dv, cnt, rev);
    k_conv1<<<dim3(NN / 2,  BB), 256, 0, stream>>>(W1, b1, idx, vals, de, dv, cnt, rev, f1);
    k_conv2<<<dim3(NN / NPB, BB), 256, 0, stream>>>(idx, vals, de, dv, cnt, rev, f1, pmax);
    k_pool2<<<BB, 256, 0, stream>>>(Wc, bc, pmax, out);
}

// Round 3
// 139.361 us; speedup vs baseline: 1.0035x; 1.0035x over previous
//
#include <hip/hip_runtime.h>
#include <math.h>

#define NN 2048
#define BB 4
#define HD 128
#define CNUM 8
#define WPB 4               // waves (= centers) per block in k_dist
#define CAP 64              // reverse-adjacency slots per node (avg in-degree = 3)
#define CAPG 128            // G-row slots per node (= 3 * in-degree, avg 9)
#define NPB 4               // nodes per block in k_conv2

typedef unsigned long long u64;

// Branchless top-3: packed key (float-bits(sq) << 32) | j. sq >= 0 so IEEE
// bits are monotonic; u64 order == (sq, j) lexicographic == reference
// tie-break (lowest j wins).
__device__ __forceinline__ u64 pack_key(float sq, int j) {
    return ((u64)__float_as_uint(sq) << 32) | (unsigned)j;
}
__device__ __forceinline__ void ins3(u64 k, u64& k0, u64& k1, u64& k2) {
    u64 a = k  < k2 ? k  : k2;   // survivor of {k, k2}
    u64 b = k0 > a  ? k0 : a;    // merge a into sorted (k0, k1)
    k0    = k0 < a  ? k0 : a;
    k2    = k1 > b  ? k1 : b;
    k1    = k1 < b  ? k1 : b;
}

// K0: pack (x,y,z,|p|^2) once to global (L2-resident, 128 KB total).
__global__ void k_prep(const float* __restrict__ x, float4* __restrict__ pts) {
    const int t = blockIdx.x * 256 + threadIdx.x;   // [0, B*NN)
    const float a = x[3 * t], c = x[3 * t + 1], d = x[3 * t + 2];
    pts[t] = make_float4(a, c, d, a * a + c * c + d * d);
}

// K1: one wave per center (round-0 proven version) + reverse-adjacency build
// in the lane-0 epilogue (3 tiny int atomics per wave).
__global__ __launch_bounds__(256) void k_dist(
        const float4* __restrict__ pts,
        int* __restrict__ idx, float* __restrict__ vals,
        float* __restrict__ de, float* __restrict__ dv,
        int* __restrict__ cnt, int2* __restrict__ rev) {
    const int b = blockIdx.y;
    const float4* pb = pts + b * NN;
    const int wave = threadIdx.x >> 6;
    const int lane = threadIdx.x & 63;
    const int i = blockIdx.x * WPB + wave;          // this wave's center
    const float4 ci = pb[i];                        // wave-uniform -> broadcast
    u64 k0 = ~0ull, k1 = ~0ull, k2 = ~0ull;
    float dsA = 0.f, dsB = 0.f;
    for (int t = lane; t < NN; t += 256) {          // 8 iterations, 4 elems each
        const float4 pa = pb[t];
        const float4 pv = pb[t + 64];
        const float4 pc = pb[t + 128];
        const float4 pd = pb[t + 192];
        const float qa = fmaxf(ci.w + pa.w - 2.0f * (ci.x * pa.x + ci.y * pa.y + ci.z * pa.z), 0.0f);
        const float qb = fmaxf(ci.w + pv.w - 2.0f * (ci.x * pv.x + ci.y * pv.y + ci.z * pv.z), 0.0f);
        const float qc = fmaxf(ci.w + pc.w - 2.0f * (ci.x * pc.x + ci.y * pc.y + ci.z * pc.z), 0.0f);
        const float qd = fmaxf(ci.w + pd.w - 2.0f * (ci.x * pd.x + ci.y * pd.y + ci.z * pd.z), 0.0f);
        dsA += __builtin_amdgcn_sqrtf(qa + 1e-12f) + __builtin_amdgcn_sqrtf(qc + 1e-12f);
        dsB += __builtin_amdgcn_sqrtf(qb + 1e-12f) + __builtin_amdgcn_sqrtf(qd + 1e-12f);
        ins3(pack_key(qa, t),       k0, k1, k2);
        ins3(pack_key(qb, t + 64),  k0, k1, k2);
        ins3(pack_key(qc, t + 128), k0, k1, k2);
        ins3(pack_key(qd, t + 192), k0, k1, k2);
    }
    float dsum = dsA + dsB;
    // butterfly merge: packed keys are globally unique -> plain u64 merge
    for (int off = 32; off > 0; off >>= 1) {
        const u64 o0 = __shfl_xor(k0, off);
        const u64 o1 = __shfl_xor(k1, off);
        const u64 o2 = __shfl_xor(k2, off);
        dsum += __shfl_xor(dsum, off);
        ins3(o0, k0, k1, k2);
        ins3(o1, k0, k1, k2);
        ins3(o2, k0, k1, k2);
    }
    if (lane == 0) {
        const float s0 = __uint_as_float((unsigned)(k0 >> 32));
        const float s1 = __uint_as_float((unsigned)(k1 >> 32));
        const float s2 = __uint_as_float((unsigned)(k2 >> 32));
        const int   i0 = (int)(k0 & 0xffffffffu);
        const int   i1 = (int)(k1 & 0xffffffffu);
        const int   i2 = (int)(k2 & 0xffffffffu);
        const float avg = dsum * (1.0f / NN);
        const float inva2 = 1.0f / (avg * avg);
        const float v0 = expf(-s0 * inva2);
        const float v1 = expf(-s1 * inva2);
        const float v2 = expf(-s2 * inva2);
        const int base = (b * NN + i) * 3;
        idx[base] = i0; idx[base + 1] = i1; idx[base + 2] = i2;
        vals[base] = v0; vals[base + 1] = v1; vals[base + 2] = v2;
        de[b * NN + i] = v0 + v1 + v2;
        atomicAdd(&dv[b * NN + i0], v0);
        atomicAdd(&dv[b * NN + i1], v1);
        atomicAdd(&dv[b * NN + i2], v2);
        // reverse adjacency: node j <- (edge i, coeff v)
        const int p0 = atomicAdd(&cnt[b * NN + i0], 1);
        if (p0 < CAP) rev[((size_t)(b * NN + i0)) * CAP + p0] = make_int2(i, __float_as_int(v0));
        const int p1 = atomicAdd(&cnt[b * NN + i1], 1);
        if (p1 < CAP) rev[((size_t)(b * NN + i1)) * CAP + p1] = make_int2(i, __float_as_int(v1));
        const int p2 = atomicAdd(&cnt[b * NN + i2], 1);
        if (p2 < CAP) rev[((size_t)(b * NN + i2)) * CAP + p2] = make_int2(i, __float_as_int(v2));
    }
}

// K2: build explicit sparse G-row per node: (j, gv) with ALL normalization
// folded in: gv = w_i * (v_ei/de_e) * v_ej * w_j. One thread per node,
// 8192 threads total -- runs once, shared by both conv passes.
__global__ void k_gbuild(const int* __restrict__ idx, const float* __restrict__ vals,
                         const float* __restrict__ de, const float* __restrict__ dv,
                         const int* __restrict__ cnt, const int2* __restrict__ rev,
                         int2* __restrict__ glist, int* __restrict__ gn) {
    const int b = blockIdx.y;
    const int i = blockIdx.x * 256 + threadIdx.x;
    const int ni = b * NN + i;
    const int cn = min(cnt[ni], CAP);
    const float wi = rsqrtf(dv[ni]);
    int m = 0;
    for (int s = 0; s < cn; ++s) {
        const int2 r = rev[(size_t)ni * CAP + s];
        const int e = r.x;
        const float coef = wi * __int_as_float(r.y) / de[b * NN + e];
        const int eb = (b * NN + e) * 3;
        #pragma unroll
        for (int t = 0; t < 3; ++t) {
            const int j = idx[eb + t];
            const float gv = coef * vals[eb + t] * rsqrtf(dv[b * NN + j]);
            if (m < CAPG) glist[(size_t)ni * CAPG + m] = make_int2(j, __float_as_int(gv));
            ++m;
        }
    }
    gn[ni] = min(m, CAPG);
}

// K3: f1 = G @ W1 + b1. Per (node, h): flat dot over ~9 precomputed entries.
// Entry loads are broadcast (uniform per half-block); W1 rows coalesced.
// Software-pipelined by one entry so both loads stay in flight.
__global__ __launch_bounds__(256) void k_conv1(
        const float* __restrict__ W1, const float* __restrict__ b1,
        const int2* __restrict__ glist, const int* __restrict__ gn,
        float* __restrict__ f1) {
    const int b = blockIdx.y;
    const int i = blockIdx.x * 2 + (threadIdx.x >> 7);
    const int h = threadIdx.x & (HD - 1);
    const int ni = b * NN + i;
    const int n = gn[ni];                 // always >= 3 (own edge)
    const int2* gl = glist + (size_t)ni * CAPG;
    float acc = b1[h];
    int2 cur = gl[0];
    for (int s = 0; s < n; ++s) {
        const int2 nxt = gl[min(s + 1, n - 1)];
        acc += __int_as_float(cur.y) * W1[cur.x * HD + h];
        cur = nxt;
    }
    f1[(size_t)ni * HD + h] = acc;
}

// K4: out = G @ f1 with fused max-pool. Monotonic-u32 encoding so the
// zero-initialized pmaxK acts as -inf and blocks merge via one u32
// atomicMax per (block, h).
__global__ __launch_bounds__(256) void k_conv2(
        const int2* __restrict__ glist, const int* __restrict__ gn,
        const float* __restrict__ f1, unsigned* __restrict__ pmaxK) {
    __shared__ float smx[2][HD];
    const int b = blockIdx.y;
    const int sub = threadIdx.x >> 7;
    const int h = threadIdx.x & (HD - 1);
    float mx = -INFINITY;
    for (int t = 0; t < NPB / 2; ++t) {
        const int i = blockIdx.x * NPB + t * 2 + sub;
        const int ni = b * NN + i;
        const int n = gn[ni];
        const int2* gl = glist + (size_t)ni * CAPG;
        float acc = 0.f;
        int2 cur = gl[0];
        for (int s = 0; s < n; ++s) {
            const int2 nxt = gl[min(s + 1, n - 1)];
            acc += __int_as_float(cur.y) * f1[((size_t)(b * NN + cur.x)) * HD + h];
            cur = nxt;
        }
        mx = fmaxf(mx, acc);
    }
    smx[sub][h] = mx;
    __syncthreads();
    if (sub == 0) {
        const float v = fmaxf(smx[0][h], smx[1][h]);
        unsigned u = __float_as_uint(v);
        u = (u & 0x80000000u) ? ~u : (u | 0x80000000u);   // monotonic encode
        atomicMax(&pmaxK[b * HD + h], u);
    }
}

// K5: decode max keys + classifier. grid B x 128 threads.
__global__ void k_cls(const float* __restrict__ Wc, const float* __restrict__ bc,
                      const unsigned* __restrict__ pmaxK, float* __restrict__ out) {
    __shared__ float smax[HD];
    const int b = blockIdx.x, h = threadIdx.x;
    unsigned u = pmaxK[b * HD + h];
    u = (u & 0x80000000u) ? (u ^ 0x80000000u) : ~u;       // decode
    smax[h] = __uint_as_float(u);
    __syncthreads();
    if (h < CNUM) {
        float acc = bc[h];
        for (int q = 0; q < HD; ++q) acc += smax[q] * Wc[q * CNUM + h];
        out[b * CNUM + h] = acc;
    }
}

extern "C" void kernel_launch(void* const* d_in, const int* in_sizes, int n_in,
                              void* d_out, int out_size, void* d_ws, size_t ws_size,
                              hipStream_t stream) {
    const float* x  = (const float*)d_in[0];   // [B,N,3]
    const float* W1 = (const float*)d_in[1];   // [N,H1]
    const float* b1 = (const float*)d_in[2];   // [H1]
    const float* Wc = (const float*)d_in[3];   // [H1,C]
    const float* bc = (const float*)d_in[4];   // [C]
    float* out = (float*)d_out;                // [B,C]

    float4*   pts   = (float4*)d_ws;                       // B*N float4
    float*    dv    = (float*)(pts + BB * NN);             // B*N   (zeroed)
    int*      cnt   = (int*)(dv + BB * NN);                // B*N   (zeroed)
    unsigned* pmaxK = (unsigned*)(cnt + BB * NN);          // B*HD  (zeroed)
    float*    de    = (float*)(pmaxK + BB * HD);           // B*N
    int*      idx   = (int*)(de + BB * NN);                // B*N*3
    float*    vals  = (float*)(idx + BB * NN * 3);         // B*N*3
    int*      gn    = (int*)(vals + BB * NN * 3);          // B*N
    int2*     rev   = (int2*)(gn + BB * NN);               // B*N*CAP
    int2*     glist = rev + (size_t)BB * NN * CAP;         // B*N*CAPG
    float*    f1    = (float*)(glist + (size_t)BB * NN * CAPG); // B*N*HD

    // zero [dv | cnt | pmaxK] (66 KB)
    hipMemsetAsync(dv, 0, (size_t)(2 * BB * NN + BB * HD) * sizeof(float), stream);

    k_prep  <<<BB * NN / 256, 256, 0, stream>>>(x, pts);
    k_dist  <<<dim3(NN / WPB, BB), 256, 0, stream>>>(pts, idx, vals, de, dv, cnt, rev);
    k_gbuild<<<dim3(NN / 256, BB), 256, 0, stream>>>(idx, vals, de, dv, cnt, rev, glist, gn);
    k_conv1 <<<dim3(NN / 2, BB), 256, 0, stream>>>(W1, b1, glist, gn, f1);
    k_conv2 <<<dim3(NN / NPB, BB), 256, 0, stream>>>(glist, gn, f1, pmaxK);
    k_cls   <<<BB, HD, 0, stream>>>(Wc, bc, pmaxK, out);
}